// Round 1
// baseline (294.273 us; speedup 1.0000x reference)
//
#include <hip/hip_runtime.h>
#include <math.h>

static constexpr int Dh = 128;
static constexpr int NH = 4;
static constexpr int NB = 16;
static constexpr int SS = 1024;
static constexpr float NEGF = -1e9f;
static constexpr float SCALE = 0.08838834764831843f;  // 1/sqrt(128)
static constexpr float LOG2E = 1.4426950408889634f;

typedef short s16x8 __attribute__((ext_vector_type(8)));
typedef short s16x4 __attribute__((ext_vector_type(4)));
typedef float f32x4 __attribute__((ext_vector_type(4)));

#define MFMA32(a, b, c) __builtin_amdgcn_mfma_f32_16x16x32_bf16(a, b, c, 0, 0, 0)
// K=16 bf16 MFMA: layouts HW-validated in prior session (r5-vs-r6 byte-identical absmax A/B).
#define MFMA16(a, b, c) __builtin_amdgcn_mfma_f32_16x16x16bf16_1k(a, b, c, 0, 0, 0)

__device__ inline ushort f2bf(float f) {
    union { float f; unsigned u; } v; v.f = f;
    unsigned r = v.u + 0x7FFFu + ((v.u >> 16) & 1u);
    return (ushort)(r >> 16);
}

// ---------------- K0: LN partial sums + bit-mask prep + weight bf16 pre-convert ----------------
__global__ __launch_bounds__(256) void ln_mask_kernel(const float* __restrict__ x,
                                                      float* __restrict__ part,
                                                      const int* __restrict__ edge,
                                                      unsigned long long* __restrict__ mbit,
                                                      const float* __restrict__ w_in,
                                                      const float* __restrict__ w_out,
                                                      ushort* __restrict__ wb,
                                                      ushort* __restrict__ wob) {
    const int b = blockIdx.x >> 4, p = blockIdx.x & 15;
    const int tid = threadIdx.x;
    const float4* xb4 = (const float4*)(x + (size_t)b * SS * Dh) + p * 2048;
    float s = 0.f, ss = 0.f;
    for (int i = tid; i < 2048; i += 256) {
        float4 v = xb4[i];
        s  += v.x + v.y + v.z + v.w;
        ss += v.x * v.x + v.y * v.y + v.z * v.z + v.w * v.w;
    }
    __shared__ float r1[256], r2[256];
    r1[tid] = s; r2[tid] = ss;
    __syncthreads();
    for (int off = 128; off > 0; off >>= 1) {
        if (tid < off) { r1[tid] += r1[tid + off]; r2[tid] += r2[tid + off]; }
        __syncthreads();
    }
    if (tid == 0) { part[blockIdx.x * 2] = r1[0]; part[blockIdx.x * 2 + 1] = r2[0]; }

    if (blockIdx.x < 64) {
        // mask prep (unchanged)
        const int idx = blockIdx.x * 256 + tid;   // < 1024*16
        const int sr = idx >> 4, w = idx & 15;
        const int4* ep = (const int4*)(edge + (size_t)sr * SS + w * 64);
        unsigned long long m0 = 0, m1 = 0, m2 = 0, m3 = 0;
        #pragma unroll
        for (int j = 0; j < 16; ++j) {
            int4 e = ep[j];
            const int base = j * 4;
            m0 |= (e.x == 1) ? (1ull << (base + 0)) : 0ull;
            m1 |= (e.x == 2) ? (1ull << (base + 0)) : 0ull;
            m2 |= (e.x == 3) ? (1ull << (base + 0)) : 0ull;
            m3 |= (e.x == 4) ? (1ull << (base + 0)) : 0ull;
            m0 |= (e.y == 1) ? (1ull << (base + 1)) : 0ull;
            m1 |= (e.y == 2) ? (1ull << (base + 1)) : 0ull;
            m2 |= (e.y == 3) ? (1ull << (base + 1)) : 0ull;
            m3 |= (e.y == 4) ? (1ull << (base + 1)) : 0ull;
            m0 |= (e.z == 1) ? (1ull << (base + 2)) : 0ull;
            m1 |= (e.z == 2) ? (1ull << (base + 2)) : 0ull;
            m2 |= (e.z == 3) ? (1ull << (base + 2)) : 0ull;
            m3 |= (e.z == 4) ? (1ull << (base + 2)) : 0ull;
            m0 |= (e.w == 1) ? (1ull << (base + 3)) : 0ull;
            m1 |= (e.w == 2) ? (1ull << (base + 3)) : 0ull;
            m2 |= (e.w == 3) ? (1ull << (base + 3)) : 0ull;
            m3 |= (e.w == 4) ? (1ull << (base + 3)) : 0ull;
        }
        mbit[((size_t)0 * SS + sr) * 16 + w] = m0;
        mbit[((size_t)1 * SS + sr) * 16 + w] = m1;
        mbit[((size_t)2 * SS + sr) * 16 + w] = m2;
        mbit[((size_t)3 * SS + sr) * 16 + w] = m3;
    } else if (blockIdx.x < 160) {
        // W_in -> bf16 : 1536*128 = 196608 elems = 24576 x 8; 96 blocks x 256 threads
        const int slot = (blockIdx.x - 64) * 256 + tid;
        const float4* sp = (const float4*)w_in + (size_t)slot * 2;
        float4 a = sp[0], c = sp[1];
        s16x8 pk;
        pk[0] = (short)f2bf(a.x); pk[1] = (short)f2bf(a.y);
        pk[2] = (short)f2bf(a.z); pk[3] = (short)f2bf(a.w);
        pk[4] = (short)f2bf(c.x); pk[5] = (short)f2bf(c.y);
        pk[6] = (short)f2bf(c.z); pk[7] = (short)f2bf(c.w);
        *(s16x8*)(wb + (size_t)slot * 8) = pk;
    } else if (blockIdx.x < 192) {
        // W_out -> bf16 : 4*128*128 = 65536 elems = 8192 x 8; 32 blocks x 256 threads
        const int slot = (blockIdx.x - 160) * 256 + tid;
        const float4* sp = (const float4*)w_out + (size_t)slot * 2;
        float4 a = sp[0], c = sp[1];
        s16x8 pk;
        pk[0] = (short)f2bf(a.x); pk[1] = (short)f2bf(a.y);
        pk[2] = (short)f2bf(a.z); pk[3] = (short)f2bf(a.w);
        pk[4] = (short)f2bf(c.x); pk[5] = (short)f2bf(c.y);
        pk[6] = (short)f2bf(c.z); pk[7] = (short)f2bf(c.w);
        *(s16x8*)(wob + (size_t)slot * 8) = pk;
    }
}

// ---------------- K0.5: xn = LN(x) -> bf16 (LN reduction finalize folded here) ----------------
__global__ __launch_bounds__(256) void xcast_kernel(const float* __restrict__ x,
                                                    const float* __restrict__ part,
                                                    ushort* __restrict__ xb) {
    const int b = blockIdx.x >> 6;       // 64 blocks per batch element (uniform per block -> scalar loads)
    float s = 0.f, ss = 0.f;
    #pragma unroll
    for (int p = 0; p < 16; ++p) { s += part[(b * 16 + p) * 2]; ss += part[(b * 16 + p) * 2 + 1]; }
    const float invN = 1.0f / (float)(SS * Dh);
    const float mu = s * invN;
    const float rstd = 1.0f / sqrtf(ss * invN - mu * mu + 1e-5f);
    const size_t base = ((size_t)blockIdx.x * 256 + threadIdx.x) * 8;
    float4 v0 = *(const float4*)(x + base);
    float4 v1 = *(const float4*)(x + base + 4);
    s16x8 pk;
    pk[0] = (short)f2bf((v0.x - mu) * rstd); pk[1] = (short)f2bf((v0.y - mu) * rstd);
    pk[2] = (short)f2bf((v0.z - mu) * rstd); pk[3] = (short)f2bf((v0.w - mu) * rstd);
    pk[4] = (short)f2bf((v1.x - mu) * rstd); pk[5] = (short)f2bf((v1.y - mu) * rstd);
    pk[6] = (short)f2bf((v1.z - mu) * rstd); pk[7] = (short)f2bf((v1.w - mu) * rstd);
    *(s16x8*)(xb + base) = pk;
}

// ---------------- K1: QKV projection, pure-bf16 MFMA (inputs pre-converted) ----------------
__global__ __launch_bounds__(256) void qkv_mfma_kernel(const ushort* __restrict__ xb,   // [16384][128] bf16 LN'd
                                                       const ushort* __restrict__ wb,   // [1536][128] bf16
                                                       const float* __restrict__ bias,  // [1536]
                                                       ushort* __restrict__ qo,
                                                       ushort* __restrict__ ko,
                                                       ushort* __restrict__ vto) {
    __shared__ ushort smem[2 * 128 * 72];     // As/Bs; epilogue alias Rs[128][136]
    ushort* As = smem;
    ushort* Bs = smem + 128 * 72;
    ushort* Rs = smem;
    const int tid = threadIdx.x, wave = tid >> 6, lane = tid & 63;
    const int lrow = lane & 15, quad = lane >> 4;
    const int wm = wave & 1, wn = wave >> 1;
    const int col0 = blockIdx.x * 128;
    const int row0 = blockIdx.y * 128;
    const int bb = row0 >> 10;

    f32x4 acc[4][4];
    #pragma unroll
    for (int mi = 0; mi < 4; ++mi)
        #pragma unroll
        for (int ni = 0; ni < 4; ++ni) acc[mi][ni] = (f32x4){0.f, 0.f, 0.f, 0.f};

    for (int kk = 0; kk < 128; kk += 64) {
        if (kk) __syncthreads();
        #pragma unroll
        for (int p = 0; p < 4; ++p) {
            int slot = p * 256 + tid;               // 1024 slots of 8 bf16
            int r = slot >> 3, c8 = (slot & 7) * 8;
            *(s16x8*)&As[r * 72 + c8] = *(const s16x8*)(xb + (size_t)(row0 + r) * Dh + kk + c8);
            *(s16x8*)&Bs[r * 72 + c8] = *(const s16x8*)(wb + (size_t)(col0 + r) * Dh + kk + c8);
        }
        __syncthreads();
        #pragma unroll
        for (int kc = 0; kc < 2; ++kc) {
            s16x8 af[4], bf[4];
            #pragma unroll
            for (int mi = 0; mi < 4; ++mi)
                af[mi] = *(const s16x8*)&As[(wm * 64 + 16 * mi + lrow) * 72 + kc * 32 + quad * 8];
            #pragma unroll
            for (int ni = 0; ni < 4; ++ni)
                bf[ni] = *(const s16x8*)&Bs[(wn * 64 + 16 * ni + lrow) * 72 + kc * 32 + quad * 8];
            #pragma unroll
            for (int mi = 0; mi < 4; ++mi)
                #pragma unroll
                for (int ni = 0; ni < 4; ++ni)
                    acc[mi][ni] = MFMA32(af[mi], bf[ni], acc[mi][ni]);
        }
    }

    const int seg = col0 % 384, typ = seg >> 7, h = col0 / 384;
    const size_t bh = (size_t)bb * NH + h;
    const int sl_blk = row0 & 1023;
    float bia[4];
    #pragma unroll
    for (int ni = 0; ni < 4; ++ni) bia[ni] = bias[col0 + wn * 64 + 16 * ni + lrow];
    // Q scaled by 1/sqrt(D) * log2(e): attention softmax runs in exp2 domain.
    const float sc = (typ == 0) ? SCALE * LOG2E : 1.f;

    __syncthreads();
    if (typ < 2) {
        #pragma unroll
        for (int mi = 0; mi < 4; ++mi)
            #pragma unroll
            for (int ni = 0; ni < 4; ++ni)
                #pragma unroll
                for (int reg = 0; reg < 4; ++reg)
                    Rs[(wm * 64 + 16 * mi + quad * 4 + reg) * 136 + wn * 64 + 16 * ni + lrow]
                        = f2bf((acc[mi][ni][reg] + bia[ni]) * sc);
    } else {
        #pragma unroll
        for (int mi = 0; mi < 4; ++mi)
            #pragma unroll
            for (int ni = 0; ni < 4; ++ni) {
                ushort4 pk;
                pk.x = f2bf(acc[mi][ni][0] + bia[ni]);
                pk.y = f2bf(acc[mi][ni][1] + bia[ni]);
                pk.z = f2bf(acc[mi][ni][2] + bia[ni]);
                pk.w = f2bf(acc[mi][ni][3] + bia[ni]);
                *(ushort4*)&Rs[(wn * 64 + 16 * ni + lrow) * 136 + wm * 64 + 16 * mi + quad * 4] = pk;
            }
    }
    __syncthreads();

    ushort* dstb;
    int pitch;
    if (typ == 0)      { dstb = qo  + bh * SS * 128 + (size_t)sl_blk * 128; pitch = 128; }
    else if (typ == 1) { dstb = ko  + bh * SS * 128 + (size_t)sl_blk * 128; pitch = 128; }
    else               { dstb = vto + bh * (size_t)128 * SS + sl_blk;       pitch = SS;  }
    #pragma unroll
    for (int p = 0; p < 8; ++p) {
        int slot = p * 256 + tid;
        int r = slot >> 4, c8 = (slot & 15) * 8;
        *(s16x8*)&dstb[(size_t)r * pitch + c8] = *(const s16x8*)&Rs[r * 136 + c8];
    }
}

// ---------------- K2: LDS-free, barrier-free flash attention; fragments direct from L1/L2 ----------------
__global__ __launch_bounds__(256, 2) void attn_fused_kernel(const ushort* __restrict__ qg_,
                                                            const ushort* __restrict__ kg_,
                                                            const ushort* __restrict__ vg_,
                                                            const unsigned long long* __restrict__ mbit,
                                                            const ushort* __restrict__ wob,   // [4][128][128] bf16
                                                            const float* __restrict__ bo,
                                                            float* __restrict__ out) {
    // 1-D grid: id%8 pins all 8 q-tiles of one (b,h) to one XCD (per-XCD KV = 4MB = L2);
    // consecutive same-XCD ids share (b,h) so co-resident CU blocks share K/V lines in L1.
    const int id = blockIdx.x;
    const int xcd = id & 7, rr = id >> 3;
    const int qt = rr & 7, bhg = rr >> 3;
    const int bhi = (bhg << 3) | xcd;
    const int b = bhi >> 2, h = bhi & 3;
    const int s0 = qt * 128;
    const int tid = threadIdx.x;
    const int wave = tid >> 6, lane = tid & 63;
    const int lrow = lane & 15, quad = lane >> 4;

    const size_t bh = (size_t)(b * NH + h);
    const ushort* qg = qg_ + bh * SS * 128;
    const ushort* kg = kg_ + bh * SS * 128;
    const ushort* vg = vg_ + bh * (size_t)128 * SS;
    const unsigned long long* mrow0 = mbit + ((size_t)h * SS + (s0 + 32 * wave + lrow)) * 16;
    const unsigned long long* mrow1 = mrow0 + 16 * 16;

    // Q fragments (B-operand of S^T MFMA32): n=q=lane&15, k=kc*32+quad*8+j
    s16x8 qf[2][4];
    #pragma unroll
    for (int g = 0; g < 2; ++g) {
        const ushort* qr = qg + (size_t)(s0 + 32 * wave + 16 * g + lrow) * 128 + quad * 8;
        #pragma unroll
        for (int kc = 0; kc < 4; ++kc) qf[g][kc] = *(const s16x8*)(qr + kc * 32);
    }

    // O^T accumulators: D[m=d][n=q]: q = lane&15, d = 16*nb+quad*4+reg
    f32x4 oacc[2][8];
    #pragma unroll
    for (int g = 0; g < 2; ++g)
        #pragma unroll
        for (int nb = 0; nb < 8; ++nb) oacc[g][nb] = (f32x4){0.f, 0.f, 0.f, 0.f};
    float m_run[2] = {-INFINITY, -INFINITY};
    float l_run[2] = {0.f, 0.f};

    for (int kt = 0; kt < 16; ++kt) {
        const int t0 = kt * 64;
        const unsigned long long mw0 = mrow0[kt];
        const unsigned long long mw1 = mrow1[kt];

        // ---- S^T = K Q'^T (exp2 domain): D[m=key][n=q]; K frags straight from global ----
        f32x4 sacc[2][4];
        #pragma unroll
        for (int g = 0; g < 2; ++g)
            #pragma unroll
            for (int cb = 0; cb < 4; ++cb) sacc[g][cb] = (f32x4){0.f, 0.f, 0.f, 0.f};
        #pragma unroll
        for (int cb = 0; cb < 4; ++cb) {
            s16x8 kf[4];
            const ushort* kr = kg + (size_t)(t0 + 16 * cb + lrow) * 128 + quad * 8;
            #pragma unroll
            for (int kc = 0; kc < 4; ++kc) kf[kc] = *(const s16x8*)(kr + kc * 32);
            #pragma unroll
            for (int kc = 0; kc < 4; ++kc) {
                sacc[0][cb] = MFMA32(kf[kc], qf[0][kc], sacc[0][cb]);
                sacc[1][cb] = MFMA32(kf[kc], qf[1][kc], sacc[1][cb]);
            }
        }

        // ---- softmax (per-lane state, q=lane&15), exp2 + deferred-max rescale ----
        s16x4 pf[2][4];
        #pragma unroll
        for (int g = 0; g < 2; ++g) {
            const unsigned long long mw = g ? mw1 : mw0;
            float sv[4][4];
            float tm = -INFINITY;
            #pragma unroll
            for (int cb = 0; cb < 4; ++cb) {
                unsigned nib = (unsigned)(mw >> (16 * cb + quad * 4)) & 0xFu;
                #pragma unroll
                for (int r = 0; r < 4; ++r) {
                    sv[cb][r] = (nib & (1u << r)) ? sacc[g][cb][r] : NEGF;
                    tm = fmaxf(tm, sv[cb][r]);
                }
            }
            tm = fmaxf(tm, __shfl_xor(tm, 16));
            tm = fmaxf(tm, __shfl_xor(tm, 32));
            float mn = m_run[g];
            // deferred-max (T13): skip O/l rescale while max grows < 12 (log2 units ~ e^8.3)
            if (!__all(tm <= mn + 12.f)) {
                mn = fmaxf(mn, tm);
                float al = __builtin_amdgcn_exp2f(m_run[g] - mn);
                l_run[g] *= al;
                #pragma unroll
                for (int nb = 0; nb < 8; ++nb)
                    #pragma unroll
                    for (int r = 0; r < 4; ++r) oacc[g][nb][r] *= al;
                m_run[g] = mn;
            }
            float rs = 0.f;
            #pragma unroll
            for (int cb = 0; cb < 4; ++cb) {
                float p0 = __builtin_amdgcn_exp2f(sv[cb][0] - mn);
                float p1 = __builtin_amdgcn_exp2f(sv[cb][1] - mn);
                float p2 = __builtin_amdgcn_exp2f(sv[cb][2] - mn);
                float p3 = __builtin_amdgcn_exp2f(sv[cb][3] - mn);
                rs += (p0 + p1) + (p2 + p3);
                s16x4 pk;
                pk[0] = (short)f2bf(p0); pk[1] = (short)f2bf(p1);
                pk[2] = (short)f2bf(p2); pk[3] = (short)f2bf(p3);
                pf[g][cb] = pk;
            }
            rs += __shfl_xor(rs, 16);
            rs += __shfl_xor(rs, 32);
            l_run[g] += rs;
        }

        // ---- O^T += V^T P^T : MFMA16, A = V^T frag direct from global, B = pf (regs) ----
        #pragma unroll
        for (int nb = 0; nb < 8; ++nb) {
            const ushort* vr = vg + (size_t)(16 * nb + lrow) * SS + t0 + quad * 4;
            #pragma unroll
            for (int kb = 0; kb < 4; ++kb) {
                s16x4 vf = *(const s16x4*)(vr + kb * 16);
                oacc[0][nb] = MFMA16(vf, pf[0][kb], oacc[0][nb]);
                oacc[1][nb] = MFMA16(vf, pf[1][kb], oacc[1][nb]);
            }
        }
    }

    // ---- fused out-projection, all-MFMA16, no LDS:
    // oacc C-layout (q=lane&15, d=quad*4+reg within 16-block) IS the MFMA16 A-operand layout.
    s16x4 aO[2][8];
    #pragma unroll
    for (int g = 0; g < 2; ++g) {
        float inv = 1.0f / l_run[g];   // per-lane, q = lane&15
        #pragma unroll
        for (int nb = 0; nb < 8; ++nb) {
            s16x4 pk;
            pk[0] = (short)f2bf(oacc[g][nb][0] * inv);
            pk[1] = (short)f2bf(oacc[g][nb][1] * inv);
            pk[2] = (short)f2bf(oacc[g][nb][2] * inv);
            pk[3] = (short)f2bf(oacc[g][nb][3] * inv);
            aO[g][nb] = pk;
        }
    }
    const ushort* wbh = wob + (size_t)h * Dh * Dh;
    const size_t orow0 = (size_t)b * SS + s0 + 32 * wave;
    #pragma unroll
    for (int eb = 0; eb < 8; ++eb) {
        float bia = bo[h * Dh + eb * 16 + lrow];
        f32x4 facc[2];
        facc[0] = (f32x4){0.f, 0.f, 0.f, 0.f};
        facc[1] = (f32x4){0.f, 0.f, 0.f, 0.f};
        const ushort* wr = wbh + (size_t)(eb * 16 + lrow) * Dh + quad * 4;
        #pragma unroll
        for (int nb = 0; nb < 8; ++nb) {
            s16x4 wf = *(const s16x4*)(wr + nb * 16);   // B[k=d][n=e]: n=lane&15=e, k=quad*4+j
            facc[0] = MFMA16(aO[0][nb], wf, facc[0]);
            facc[1] = MFMA16(aO[1][nb], wf, facc[1]);
        }
        #pragma unroll
        for (int g = 0; g < 2; ++g)
            #pragma unroll
            for (int reg = 0; reg < 4; ++reg) {
                size_t m = orow0 + 16 * g + quad * 4 + reg;
                out[m * (NH * Dh) + h * Dh + eb * 16 + lrow] = facc[g][reg] + bia;
            }
    }
}

extern "C" void kernel_launch(void* const* d_in, const int* in_sizes, int n_in,
                              void* d_out, int out_size, void* d_ws, size_t ws_size,
                              hipStream_t stream) {
    const float* x     = (const float*)d_in[0];
    const int*   edge  = (const int*)d_in[1];
    const float* w_in  = (const float*)d_in[2];
    const float* b_in  = (const float*)d_in[3];
    const float* w_out = (const float*)d_in[4];
    const float* b_out = (const float*)d_in[5];
    float* out = (float*)d_out;

    float* ws   = (float*)d_ws;
    float* part = ws;                                              // 512 floats (reserve 1024)
    unsigned long long* mbit = (unsigned long long*)(ws + 1024);   // [4][1024][16] u64 = 512 KB
    ushort* qo  = (ushort*)(mbit + (size_t)NH * SS * 16);
    const size_t QSZ = (size_t)NB * NH * SS * 128;
    ushort* ko  = qo + QSZ;
    ushort* vto = ko + QSZ;                                        // [b][h][128][s]
    ushort* xb  = vto + QSZ;                                       // [16384][128] bf16 LN'd x (4 MB)
    ushort* wb  = xb + (size_t)NB * SS * Dh;                       // [1536][128] bf16 W_in
    ushort* wob = wb + (size_t)NH * 3 * Dh * Dh;                   // [4][128][128] bf16 W_out

    ln_mask_kernel<<<256, 256, 0, stream>>>(x, part, edge, mbit, w_in, w_out, wb, wob);
    xcast_kernel<<<1024, 256, 0, stream>>>(x, part, xb);
    qkv_mfma_kernel<<<dim3(12, 128), 256, 0, stream>>>(xb, wb, b_in, qo, ko, vto);
    attn_fused_kernel<<<512, 256, 0, stream>>>(qo, ko, vto, mbit, wob, b_out, out);
}

// Round 2
// 165.841 us; speedup vs baseline: 1.7744x; 1.7744x over previous
//
#include <hip/hip_runtime.h>
#include <math.h>

static constexpr int Dh = 128;
static constexpr int NH = 4;
static constexpr int NB = 16;
static constexpr int SS = 1024;
static constexpr float NEGF = -1e9f;
static constexpr float SCALE = 0.08838834764831843f;  // 1/sqrt(128)
static constexpr float LOG2E = 1.4426950408889634f;

typedef short s16x8 __attribute__((ext_vector_type(8)));
typedef short s16x4 __attribute__((ext_vector_type(4)));
typedef float f32x4 __attribute__((ext_vector_type(4)));

#define MFMA32(a, b, c) __builtin_amdgcn_mfma_f32_16x16x32_bf16(a, b, c, 0, 0, 0)
// K=16 bf16 MFMA: layouts HW-validated in prior session (byte-identical absmax A/B).
#define MFMA16(a, b, c) __builtin_amdgcn_mfma_f32_16x16x16bf16_1k(a, b, c, 0, 0, 0)

__device__ inline ushort f2bf(float f) {
    union { float f; unsigned u; } v; v.f = f;
    unsigned r = v.u + 0x7FFFu + ((v.u >> 16) & 1u);
    return (ushort)(r >> 16);
}

// ---------------- K0: LN partial sums + bit-mask prep + weight bf16 pre-convert ----------------
__global__ __launch_bounds__(256) void ln_mask_kernel(const float* __restrict__ x,
                                                      float* __restrict__ part,
                                                      const int* __restrict__ edge,
                                                      unsigned long long* __restrict__ mbit,
                                                      const float* __restrict__ w_in,
                                                      const float* __restrict__ w_out,
                                                      ushort* __restrict__ wb,
                                                      ushort* __restrict__ wob) {
    const int b = blockIdx.x >> 4, p = blockIdx.x & 15;
    const int tid = threadIdx.x;
    const float4* xb4 = (const float4*)(x + (size_t)b * SS * Dh) + p * 2048;
    float s = 0.f, ss = 0.f;
    for (int i = tid; i < 2048; i += 256) {
        float4 v = xb4[i];
        s  += v.x + v.y + v.z + v.w;
        ss += v.x * v.x + v.y * v.y + v.z * v.z + v.w * v.w;
    }
    __shared__ float r1[256], r2[256];
    r1[tid] = s; r2[tid] = ss;
    __syncthreads();
    for (int off = 128; off > 0; off >>= 1) {
        if (tid < off) { r1[tid] += r1[tid + off]; r2[tid] += r2[tid + off]; }
        __syncthreads();
    }
    if (tid == 0) { part[blockIdx.x * 2] = r1[0]; part[blockIdx.x * 2 + 1] = r2[0]; }

    if (blockIdx.x < 64) {
        const int idx = blockIdx.x * 256 + tid;   // < 1024*16
        const int sr = idx >> 4, w = idx & 15;
        const int4* ep = (const int4*)(edge + (size_t)sr * SS + w * 64);
        unsigned long long m0 = 0, m1 = 0, m2 = 0, m3 = 0;
        #pragma unroll
        for (int j = 0; j < 16; ++j) {
            int4 e = ep[j];
            const int base = j * 4;
            m0 |= (e.x == 1) ? (1ull << (base + 0)) : 0ull;
            m1 |= (e.x == 2) ? (1ull << (base + 0)) : 0ull;
            m2 |= (e.x == 3) ? (1ull << (base + 0)) : 0ull;
            m3 |= (e.x == 4) ? (1ull << (base + 0)) : 0ull;
            m0 |= (e.y == 1) ? (1ull << (base + 1)) : 0ull;
            m1 |= (e.y == 2) ? (1ull << (base + 1)) : 0ull;
            m2 |= (e.y == 3) ? (1ull << (base + 1)) : 0ull;
            m3 |= (e.y == 4) ? (1ull << (base + 1)) : 0ull;
            m0 |= (e.z == 1) ? (1ull << (base + 2)) : 0ull;
            m1 |= (e.z == 2) ? (1ull << (base + 2)) : 0ull;
            m2 |= (e.z == 3) ? (1ull << (base + 2)) : 0ull;
            m3 |= (e.z == 4) ? (1ull << (base + 2)) : 0ull;
            m0 |= (e.w == 1) ? (1ull << (base + 3)) : 0ull;
            m1 |= (e.w == 2) ? (1ull << (base + 3)) : 0ull;
            m2 |= (e.w == 3) ? (1ull << (base + 3)) : 0ull;
            m3 |= (e.w == 4) ? (1ull << (base + 3)) : 0ull;
        }
        mbit[((size_t)0 * SS + sr) * 16 + w] = m0;
        mbit[((size_t)1 * SS + sr) * 16 + w] = m1;
        mbit[((size_t)2 * SS + sr) * 16 + w] = m2;
        mbit[((size_t)3 * SS + sr) * 16 + w] = m3;
    } else if (blockIdx.x < 160) {
        // W_in -> bf16 : 1536*128 elems; 96 blocks x 256 threads x 8
        const int slot = (blockIdx.x - 64) * 256 + tid;
        const float4* sp = (const float4*)w_in + (size_t)slot * 2;
        float4 a = sp[0], c = sp[1];
        s16x8 pk;
        pk[0] = (short)f2bf(a.x); pk[1] = (short)f2bf(a.y);
        pk[2] = (short)f2bf(a.z); pk[3] = (short)f2bf(a.w);
        pk[4] = (short)f2bf(c.x); pk[5] = (short)f2bf(c.y);
        pk[6] = (short)f2bf(c.z); pk[7] = (short)f2bf(c.w);
        *(s16x8*)(wb + (size_t)slot * 8) = pk;
    } else if (blockIdx.x < 192) {
        // W_out -> bf16 : 4*128*128 elems; 32 blocks x 256 threads x 8
        const int slot = (blockIdx.x - 160) * 256 + tid;
        const float4* sp = (const float4*)w_out + (size_t)slot * 2;
        float4 a = sp[0], c = sp[1];
        s16x8 pk;
        pk[0] = (short)f2bf(a.x); pk[1] = (short)f2bf(a.y);
        pk[2] = (short)f2bf(a.z); pk[3] = (short)f2bf(a.w);
        pk[4] = (short)f2bf(c.x); pk[5] = (short)f2bf(c.y);
        pk[6] = (short)f2bf(c.z); pk[7] = (short)f2bf(c.w);
        *(s16x8*)(wob + (size_t)slot * 8) = pk;
    }
}

// ---------------- K0.5: xn = LN(x) -> bf16 ----------------
__global__ __launch_bounds__(256) void xcast_kernel(const float* __restrict__ x,
                                                    const float* __restrict__ part,
                                                    ushort* __restrict__ xb) {
    const int b = blockIdx.x >> 6;
    float s = 0.f, ss = 0.f;
    #pragma unroll
    for (int p = 0; p < 16; ++p) { s += part[(b * 16 + p) * 2]; ss += part[(b * 16 + p) * 2 + 1]; }
    const float invN = 1.0f / (float)(SS * Dh);
    const float mu = s * invN;
    const float rstd = 1.0f / sqrtf(ss * invN - mu * mu + 1e-5f);
    const size_t base = ((size_t)blockIdx.x * 256 + threadIdx.x) * 8;
    float4 v0 = *(const float4*)(x + base);
    float4 v1 = *(const float4*)(x + base + 4);
    s16x8 pk;
    pk[0] = (short)f2bf((v0.x - mu) * rstd); pk[1] = (short)f2bf((v0.y - mu) * rstd);
    pk[2] = (short)f2bf((v0.z - mu) * rstd); pk[3] = (short)f2bf((v0.w - mu) * rstd);
    pk[4] = (short)f2bf((v1.x - mu) * rstd); pk[5] = (short)f2bf((v1.y - mu) * rstd);
    pk[6] = (short)f2bf((v1.z - mu) * rstd); pk[7] = (short)f2bf((v1.w - mu) * rstd);
    *(s16x8*)(xb + base) = pk;
}

// ---------------- K1: QKV projection, pure-bf16 MFMA ----------------
__global__ __launch_bounds__(256) void qkv_mfma_kernel(const ushort* __restrict__ xb,   // [16384][128] bf16 LN'd
                                                       const ushort* __restrict__ wb,   // [1536][128] bf16
                                                       const float* __restrict__ bias,  // [1536]
                                                       ushort* __restrict__ qo,
                                                       ushort* __restrict__ ko,
                                                       ushort* __restrict__ vto) {
    __shared__ ushort smem[2 * 128 * 72];     // As/Bs; epilogue alias Rs[128][136]
    ushort* As = smem;
    ushort* Bs = smem + 128 * 72;
    ushort* Rs = smem;
    const int tid = threadIdx.x, wave = tid >> 6, lane = tid & 63;
    const int lrow = lane & 15, quad = lane >> 4;
    const int wm = wave & 1, wn = wave >> 1;
    const int col0 = blockIdx.x * 128;
    const int row0 = blockIdx.y * 128;
    const int bb = row0 >> 10;

    f32x4 acc[4][4];
    #pragma unroll
    for (int mi = 0; mi < 4; ++mi)
        #pragma unroll
        for (int ni = 0; ni < 4; ++ni) acc[mi][ni] = (f32x4){0.f, 0.f, 0.f, 0.f};

    for (int kk = 0; kk < 128; kk += 64) {
        if (kk) __syncthreads();
        #pragma unroll
        for (int p = 0; p < 4; ++p) {
            int slot = p * 256 + tid;               // 1024 slots of 8 bf16
            int r = slot >> 3, c8 = (slot & 7) * 8;
            *(s16x8*)&As[r * 72 + c8] = *(const s16x8*)(xb + (size_t)(row0 + r) * Dh + kk + c8);
            *(s16x8*)&Bs[r * 72 + c8] = *(const s16x8*)(wb + (size_t)(col0 + r) * Dh + kk + c8);
        }
        __syncthreads();
        #pragma unroll
        for (int kc = 0; kc < 2; ++kc) {
            s16x8 af[4], bf[4];
            #pragma unroll
            for (int mi = 0; mi < 4; ++mi)
                af[mi] = *(const s16x8*)&As[(wm * 64 + 16 * mi + lrow) * 72 + kc * 32 + quad * 8];
            #pragma unroll
            for (int ni = 0; ni < 4; ++ni)
                bf[ni] = *(const s16x8*)&Bs[(wn * 64 + 16 * ni + lrow) * 72 + kc * 32 + quad * 8];
            #pragma unroll
            for (int mi = 0; mi < 4; ++mi)
                #pragma unroll
                for (int ni = 0; ni < 4; ++ni)
                    acc[mi][ni] = MFMA32(af[mi], bf[ni], acc[mi][ni]);
        }
    }

    const int seg = col0 % 384, typ = seg >> 7, h = col0 / 384;
    const size_t bh = (size_t)bb * NH + h;
    const int sl_blk = row0 & 1023;
    float bia[4];
    #pragma unroll
    for (int ni = 0; ni < 4; ++ni) bia[ni] = bias[col0 + wn * 64 + 16 * ni + lrow];
    // Q scaled by 1/sqrt(D) * log2(e): attention softmax runs in exp2 domain.
    const float sc = (typ == 0) ? SCALE * LOG2E : 1.f;

    __syncthreads();
    if (typ < 2) {
        #pragma unroll
        for (int mi = 0; mi < 4; ++mi)
            #pragma unroll
            for (int ni = 0; ni < 4; ++ni)
                #pragma unroll
                for (int reg = 0; reg < 4; ++reg)
                    Rs[(wm * 64 + 16 * mi + quad * 4 + reg) * 136 + wn * 64 + 16 * ni + lrow]
                        = f2bf((acc[mi][ni][reg] + bia[ni]) * sc);
    } else {
        #pragma unroll
        for (int mi = 0; mi < 4; ++mi)
            #pragma unroll
            for (int ni = 0; ni < 4; ++ni) {
                ushort4 pk;
                pk.x = f2bf(acc[mi][ni][0] + bia[ni]);
                pk.y = f2bf(acc[mi][ni][1] + bia[ni]);
                pk.z = f2bf(acc[mi][ni][2] + bia[ni]);
                pk.w = f2bf(acc[mi][ni][3] + bia[ni]);
                *(ushort4*)&Rs[(wn * 64 + 16 * ni + lrow) * 136 + wm * 64 + 16 * mi + quad * 4] = pk;
            }
    }
    __syncthreads();

    ushort* dstb;
    int pitch;
    if (typ == 0)      { dstb = qo  + bh * SS * 128 + (size_t)sl_blk * 128; pitch = 128; }
    else if (typ == 1) { dstb = ko  + bh * SS * 128 + (size_t)sl_blk * 128; pitch = 128; }
    else               { dstb = vto + bh * (size_t)128 * SS + sl_blk;       pitch = SS;  }
    #pragma unroll
    for (int p = 0; p < 8; ++p) {
        int slot = p * 256 + tid;
        int r = slot >> 4, c8 = (slot & 15) * 8;
        *(s16x8*)&dstb[(size_t)r * pitch + c8] = *(const s16x8*)&Rs[r * 136 + c8];
    }
}

// ---------------- K2: MFMA flash attention; double-buffered LDS (1 barrier/tile);
//                  XOR-swizzled Ks; exp2 softmax + deferred rescale; register out-proj ----------------
static constexpr int VT_LD = 72;
static constexpr int HALF = 64 * 128 + 128 * VT_LD;   // 17408 ushorts per buffer

__global__ __launch_bounds__(256, 2) void attn_fused_kernel(const ushort* __restrict__ qg_,
                                                            const ushort* __restrict__ kg_,
                                                            const ushort* __restrict__ vg_,
                                                            const unsigned long long* __restrict__ mbit,
                                                            const ushort* __restrict__ wob,   // [4][128][128] bf16
                                                            const float* __restrict__ bo,
                                                            float* __restrict__ out) {
    // blockIdx.x = (b,h): all 8 q-tiles of a (b,h) share id%8 -> same XCD L2
    const int bhi = blockIdx.x, qt = blockIdx.y;
    const int b = bhi >> 2, h = bhi & 3;
    const int s0 = qt * 128;
    const int tid = threadIdx.x;
    const int wave = tid >> 6, lane = tid & 63;
    const int lrow = lane & 15, quad = lane >> 4;

    __shared__ ushort smem[2 * HALF];

    const size_t bh = (size_t)(b * NH + h);
    const ushort* qg = qg_ + bh * SS * 128;
    const ushort* kg = kg_ + bh * SS * 128;
    const ushort* vg = vg_ + bh * (size_t)128 * SS;
    const unsigned long long* mrow0 = mbit + ((size_t)h * SS + (s0 + 32 * wave + lrow)) * 16;
    const unsigned long long* mrow1 = mrow0 + 16 * 16;

    // Q fragments (B-operand of S^T MFMA32): n=q=lane&15, k=kc*32+quad*8+j
    s16x8 qf[2][4];
    #pragma unroll
    for (int g = 0; g < 2; ++g) {
        const ushort* qr = qg + (size_t)(s0 + 32 * wave + 16 * g + lrow) * 128 + quad * 8;
        #pragma unroll
        for (int kc = 0; kc < 4; ++kc) qf[g][kc] = *(const s16x8*)(qr + kc * 32);
    }

    // staging regs + prologue: stage tile 0 into buffer 0
    s16x8 kreg[4], vreg[4];
    #pragma unroll
    for (int p = 0; p < 4; ++p) {
        int slot = p * 256 + tid;
        int r = slot >> 4, c = (slot & 15) * 8;
        kreg[p] = *(const s16x8*)(kg + (size_t)r * 128 + c);
    }
    #pragma unroll
    for (int p = 0; p < 4; ++p) {
        int slot = p * 256 + tid;
        int r = slot >> 3, c = (slot & 7) * 8;
        vreg[p] = *(const s16x8*)(vg + (size_t)r * SS + c);
    }
    {
        ushort* Ks0 = smem;
        ushort* Vt0 = smem + 64 * 128;
        #pragma unroll
        for (int p = 0; p < 4; ++p) {
            int slot = p * 256 + tid;
            int r = slot >> 4, c = (slot & 15) * 8;
            *(s16x8*)&Ks0[r * 128 + (c ^ ((r & 7) << 3))] = kreg[p];   // XOR-swizzled
        }
        #pragma unroll
        for (int p = 0; p < 4; ++p) {
            int slot = p * 256 + tid;
            int r = slot >> 3, c = (slot & 7) * 8;
            *(s16x8*)&Vt0[r * VT_LD + c] = vreg[p];
        }
    }

    // O^T accumulators: D[m=d][n=q]: q = lane&15, d = 16*nb+quad*4+reg
    f32x4 oacc[2][8];
    #pragma unroll
    for (int g = 0; g < 2; ++g)
        #pragma unroll
        for (int nb = 0; nb < 8; ++nb) oacc[g][nb] = (f32x4){0.f, 0.f, 0.f, 0.f};
    float m_run[2] = {-INFINITY, -INFINITY};
    float l_run[2] = {0.f, 0.f};

    for (int kt = 0; kt < 16; ++kt) {
        const unsigned long long mw0 = mrow0[kt];
        const unsigned long long mw1 = mrow1[kt];
        const ushort* Ksc = smem + (kt & 1) * HALF;
        const ushort* Vtc = Ksc + 64 * 128;

        __syncthreads();   // single barrier: cur-buffer writes visible; next-buffer reads (iter kt-1) done

        // issue next-tile global loads (latency hidden under QK+softmax+PV)
        if (kt < 15) {
            const int t1 = (kt + 1) * 64;
            #pragma unroll
            for (int p = 0; p < 4; ++p) {
                int slot = p * 256 + tid;
                int r = slot >> 4, c = (slot & 15) * 8;
                kreg[p] = *(const s16x8*)(kg + (size_t)(t1 + r) * 128 + c);
            }
            #pragma unroll
            for (int p = 0; p < 4; ++p) {
                int slot = p * 256 + tid;
                int r = slot >> 3, c = (slot & 7) * 8;
                vreg[p] = *(const s16x8*)(vg + (size_t)r * SS + t1 + c);
            }
        }

        // ---- S^T = K Q'^T : D[m=key][n=q]; key = 16*cb+quad*4+reg, q = lane&15 ----
        f32x4 sacc[2][4];
        #pragma unroll
        for (int g = 0; g < 2; ++g)
            #pragma unroll
            for (int cb = 0; cb < 4; ++cb) sacc[g][cb] = (f32x4){0.f, 0.f, 0.f, 0.f};
        __builtin_amdgcn_s_setprio(1);
        #pragma unroll
        for (int cb = 0; cb < 4; ++cb) {
            s16x8 kf[4];
            const int krow = 16 * cb + lrow;
            #pragma unroll
            for (int kc = 0; kc < 4; ++kc)
                kf[kc] = *(const s16x8*)&Ksc[krow * 128 + ((kc * 32 + quad * 8) ^ ((lrow & 7) << 3))];
            #pragma unroll
            for (int kc = 0; kc < 4; ++kc) {
                sacc[0][cb] = MFMA32(kf[kc], qf[0][kc], sacc[0][cb]);
                sacc[1][cb] = MFMA32(kf[kc], qf[1][kc], sacc[1][cb]);
            }
        }
        __builtin_amdgcn_s_setprio(0);

        // ---- softmax (per-lane state, q=lane&15), exp2 domain + deferred-max rescale ----
        s16x4 pf[2][4];
        #pragma unroll
        for (int g = 0; g < 2; ++g) {
            const unsigned long long mw = g ? mw1 : mw0;
            float sv[4][4];
            float tm = -INFINITY;
            #pragma unroll
            for (int cb = 0; cb < 4; ++cb) {
                unsigned nib = (unsigned)(mw >> (16 * cb + quad * 4)) & 0xFu;
                #pragma unroll
                for (int r = 0; r < 4; ++r) {
                    sv[cb][r] = (nib & (1u << r)) ? sacc[g][cb][r] : NEGF;
                    tm = fmaxf(tm, sv[cb][r]);
                }
            }
            tm = fmaxf(tm, __shfl_xor(tm, 16));
            tm = fmaxf(tm, __shfl_xor(tm, 32));
            float mn = m_run[g];
            // deferred-max (T13): skip O/l rescale while max grows < 12 log2-units (~e^8.3)
            if (!__all(tm <= mn + 12.f)) {
                mn = fmaxf(mn, tm);
                float al = __builtin_amdgcn_exp2f(m_run[g] - mn);
                l_run[g] *= al;
                #pragma unroll
                for (int nb = 0; nb < 8; ++nb)
                    #pragma unroll
                    for (int r = 0; r < 4; ++r) oacc[g][nb][r] *= al;
                m_run[g] = mn;
            }
            float rs = 0.f;
            #pragma unroll
            for (int cb = 0; cb < 4; ++cb) {
                float p0 = __builtin_amdgcn_exp2f(sv[cb][0] - mn);
                float p1 = __builtin_amdgcn_exp2f(sv[cb][1] - mn);
                float p2 = __builtin_amdgcn_exp2f(sv[cb][2] - mn);
                float p3 = __builtin_amdgcn_exp2f(sv[cb][3] - mn);
                rs += (p0 + p1) + (p2 + p3);
                s16x4 pk;
                pk[0] = (short)f2bf(p0); pk[1] = (short)f2bf(p1);
                pk[2] = (short)f2bf(p2); pk[3] = (short)f2bf(p3);
                pf[g][cb] = pk;
            }
            rs += __shfl_xor(rs, 16);
            rs += __shfl_xor(rs, 32);
            l_run[g] += rs;
        }

        // ---- O^T += V^T P^T : MFMA16, A = V^T frag (LDS), B = pf (registers) ----
        __builtin_amdgcn_s_setprio(1);
        #pragma unroll
        for (int nb = 0; nb < 8; ++nb) {
            #pragma unroll
            for (int kb = 0; kb < 4; ++kb) {
                s16x4 vf = *(const s16x4*)&Vtc[(16 * nb + lrow) * VT_LD + kb * 16 + quad * 4];
                oacc[0][nb] = MFMA16(vf, pf[0][kb], oacc[0][nb]);
                oacc[1][nb] = MFMA16(vf, pf[1][kb], oacc[1][nb]);
            }
        }
        __builtin_amdgcn_s_setprio(0);

        // ---- write next tile into the other buffer (protected by next iter's barrier) ----
        if (kt < 15) {
            ushort* Ksn = smem + ((kt + 1) & 1) * HALF;
            ushort* Vtn = Ksn + 64 * 128;
            #pragma unroll
            for (int p = 0; p < 4; ++p) {
                int slot = p * 256 + tid;
                int r = slot >> 4, c = (slot & 15) * 8;
                *(s16x8*)&Ksn[r * 128 + (c ^ ((r & 7) << 3))] = kreg[p];
            }
            #pragma unroll
            for (int p = 0; p < 4; ++p) {
                int slot = p * 256 + tid;
                int r = slot >> 3, c = (slot & 7) * 8;
                *(s16x8*)&Vtn[r * VT_LD + c] = vreg[p];
            }
        }
    }

    // ---- fused out-projection, all-MFMA16, register-only:
    // oacc C-layout (q=lane&15, d=quad*4+reg within 16-block) IS the MFMA16 A-operand layout.
    s16x4 aO[2][8];
    #pragma unroll
    for (int g = 0; g < 2; ++g) {
        float inv = 1.0f / l_run[g];   // per-lane, q = lane&15
        #pragma unroll
        for (int nb = 0; nb < 8; ++nb) {
            s16x4 pk;
            pk[0] = (short)f2bf(oacc[g][nb][0] * inv);
            pk[1] = (short)f2bf(oacc[g][nb][1] * inv);
            pk[2] = (short)f2bf(oacc[g][nb][2] * inv);
            pk[3] = (short)f2bf(oacc[g][nb][3] * inv);
            aO[g][nb] = pk;
        }
    }
    const ushort* wbh = wob + (size_t)h * Dh * Dh;
    const size_t orow0 = (size_t)b * SS + s0 + 32 * wave;
    #pragma unroll
    for (int eb = 0; eb < 8; ++eb) {
        float bia = bo[h * Dh + eb * 16 + lrow];
        f32x4 facc[2];
        facc[0] = (f32x4){0.f, 0.f, 0.f, 0.f};
        facc[1] = (f32x4){0.f, 0.f, 0.f, 0.f};
        const ushort* wr = wbh + (size_t)(eb * 16 + lrow) * Dh + quad * 4;
        #pragma unroll
        for (int nb = 0; nb < 8; ++nb) {
            s16x4 wf = *(const s16x4*)(wr + nb * 16);   // B[k=d][n=e]: n=lane&15=e, k=quad*4+j
            facc[0] = MFMA16(aO[0][nb], wf, facc[0]);
            facc[1] = MFMA16(aO[1][nb], wf, facc[1]);
        }
        #pragma unroll
        for (int g = 0; g < 2; ++g)
            #pragma unroll
            for (int reg = 0; reg < 4; ++reg) {
                size_t m = orow0 + 16 * g + quad * 4 + reg;
                out[m * (NH * Dh) + h * Dh + eb * 16 + lrow] = facc[g][reg] + bia;
            }
    }
}

extern "C" void kernel_launch(void* const* d_in, const int* in_sizes, int n_in,
                              void* d_out, int out_size, void* d_ws, size_t ws_size,
                              hipStream_t stream) {
    const float* x     = (const float*)d_in[0];
    const int*   edge  = (const int*)d_in[1];
    const float* w_in  = (const float*)d_in[2];
    const float* b_in  = (const float*)d_in[3];
    const float* w_out = (const float*)d_in[4];
    const float* b_out = (const float*)d_in[5];
    float* out = (float*)d_out;

    float* ws   = (float*)d_ws;
    float* part = ws;                                              // 512 floats (reserve 1024)
    unsigned long long* mbit = (unsigned long long*)(ws + 1024);   // [4][1024][16] u64 = 512 KB
    ushort* qo  = (ushort*)(mbit + (size_t)NH * SS * 16);
    const size_t QSZ = (size_t)NB * NH * SS * 128;
    ushort* ko  = qo + QSZ;
    ushort* vto = ko + QSZ;                                        // [b][h][128][s]
    ushort* xb  = vto + QSZ;                                       // [16384][128] bf16 LN'd x (4 MB)
    ushort* wb  = xb + (size_t)NB * SS * Dh;                       // [1536][128] bf16 W_in
    ushort* wob = wb + (size_t)NH * 3 * Dh * Dh;                   // [4][128][128] bf16 W_out

    ln_mask_kernel<<<256, 256, 0, stream>>>(x, part, edge, mbit, w_in, w_out, wb, wob);
    xcast_kernel<<<1024, 256, 0, stream>>>(x, part, xb);
    qkv_mfma_kernel<<<dim3(12, 128), 256, 0, stream>>>(xb, wb, b_in, qo, ko, vto);
    attn_fused_kernel<<<dim3(NB * NH, SS / 128), 256, 0, stream>>>(qo, ko, vto, mbit, wob, b_out, out);
}